// Round 20
// baseline (104.216 us; speedup 1.0000x reference)
//
#include <hip/hip_runtime.h>

#define N_NODES 50000
#define N_EDGES 600000
#define D 128
#define LAYERS 2
#define NAL 50048     // N_NODES rounded up to 64
#define CAP 48        // ELL slots per row
#define NB1 256       // phase-1 binning blocks
#define EPB 2344      // edges per binning block (256*2344 >= 600000)
#define NBINS 256
#define BIN_ROWS 196  // 256*196 = 50176 >= N_NODES
#define FRAG_CAP 32   // per-(block,bin) fragment cap; Poisson(9.2) -> P(>32)~1e-10
#define PBLOCKS 6250  // prep: 1.6M float4 elements / 256

typedef short bf16x8 __attribute__((ext_vector_type(8)));
typedef float f32x4 __attribute__((ext_vector_type(4)));
typedef float f32x2 __attribute__((ext_vector_type(2)));
typedef uint  u32x4 __attribute__((ext_vector_type(4)));

__device__ __forceinline__ ushort f2b(float f) {
  uint u = __float_as_uint(f);
  return (ushort)((u + 0x7fffu + ((u >> 16) & 1u)) >> 16);
}
__device__ __forceinline__ float b2f_lo(uint p) { return __uint_as_float(p << 16); }
__device__ __forceinline__ float b2f_hi(uint p) { return __uint_as_float(p & 0xffff0000u); }

// ---- dispatch 1: edge binning (blocks 0..255, LDS cursors only) + prep ----
__global__ __launch_bounds__(256) void k_bin_prep(
    const int* __restrict__ row, const int* __restrict__ col,
    const float* __restrict__ vals,
    uint2* __restrict__ staging, int* __restrict__ bcnt,
    const float* __restrict__ X, const float* __restrict__ W,
    ushort* __restrict__ Xb, ushort* __restrict__ Wb,
    uint* __restrict__ X8a, uint* __restrict__ X8b) {
  const int blk = blockIdx.x;
  const int t = threadIdx.x;
  if (blk < NB1) {
    __shared__ int lcur[NBINS];
    lcur[t] = 0;                       // 256 threads == NBINS
    __syncthreads();
    const int e0 = blk * EPB;
    for (int i = t; i < EPB; i += 256) {
      int e = e0 + i;
      if (e < N_EDGES) {
        int r = row[e];
        int bin = r / BIN_ROWS;        // 0..255 (compiler magic-mul)
        int slot = atomicAdd(&lcur[bin], 1);   // LDS atomic
        if (slot < FRAG_CAP) {
          uint cv = ((uint)f2b(vals[e]) << 16) | (uint)col[e];
          staging[((size_t)blk * NBINS + bin) * FRAG_CAP + slot] =
              make_uint2(cv, (uint)r);
        }
      }
    }
    __syncthreads();
    bcnt[blk * NBINS + t] = min(lcur[t], FRAG_CAP);
  } else {
    // ---- prep: X -> bf16 (diag) + split fp8 halves; W -> bf16 ----
    int i = (blk - NB1) * 256 + t;
    if (i < N_NODES * D / 4) {
      float4 v = ((const float4*)X)[i];
      ushort4 o;
      o.x = f2b(v.x); o.y = f2b(v.y); o.z = f2b(v.z); o.w = f2b(v.w);
      ((ushort4*)Xb)[i] = o;
      int pk = __builtin_amdgcn_cvt_pk_fp8_f32(v.x, v.y, 0, false);
      pk = __builtin_amdgcn_cvt_pk_fp8_f32(v.z, v.w, pk, true);
      int r = i >> 5, cg = i & 31;     // 32 float4-groups per row
      if (cg < 16) X8a[r * 16 + cg] = (uint)pk;
      else         X8b[r * 16 + cg - 16] = (uint)pk;
    }
    if (i < LAYERS * D * D / 4) {
      float4 v = ((const float4*)W)[i];
      ushort4 o;
      o.x = f2b(v.x); o.y = f2b(v.y); o.z = f2b(v.z); o.w = f2b(v.w);
      ((ushort4*)Wb)[i] = o;
    }
  }
}

// ---- dispatch 2: per-bin ELL scatter (LDS cursors, L2-hot windows) ----
__global__ __launch_bounds__(256) void k_scatter(
    const uint2* __restrict__ staging, const int* __restrict__ bcnt,
    int* __restrict__ counts, uint* __restrict__ ell) {
  const int b = blockIdx.x;            // bin
  const int t = threadIdx.x;
  __shared__ int lcur[BIN_ROWS];
  for (int i = t; i < BIN_ROWS; i += 256) lcur[i] = 0;
  __syncthreads();
  const int rbase = b * BIN_ROWS;
  const int n = bcnt[t * NBINS + b];
  const uint2* frag = staging + ((size_t)t * NBINS + b) * FRAG_CAP;
  for (int k = 0; k < n; ++k) {
    uint2 E = frag[k];
    int rl = (int)E.y - rbase;
    int slot = atomicAdd(&lcur[rl], 1);          // LDS atomic
    if (slot < CAP) ell[(size_t)E.y * CAP + slot] = E.x;
  }
  __syncthreads();
  for (int i = t; i < BIN_ROWS; i += 256) {
    int r = rbase + i;
    if (r < NAL) counts[r] = lcur[i];
  }
}

// 8-edge pipelined gather over a 64-col fp8 half-array (row stride 64 B).
// 8 lanes/node, lane owns 8 cols. Accumulation order per column identical
// to the full-row kernel -> bit-identical results.
#define GATHER_HALF(X8)                                                      \
    float a0 = 0.f, a1 = 0.f, a2 = 0.f, a3 = 0.f;                            \
    float a4 = 0.f, a5 = 0.f, a6 = 0.f, a7 = 0.f;                            \
    {                                                                        \
      uint4 ea = *(const uint4*)(ep);                                        \
      uint4 eb = *(const uint4*)(ep + 4);                                    \
      int j = 0;                                                             \
      for (; j + 8 <= cnt; j += 8) {                                         \
        uint4 na = *(const uint4*)(ep + j + 8);                              \
        uint4 nb = *(const uint4*)(ep + j + 12);                             \
        uint2 q0 = *(const uint2*)((X8) + ((size_t)(ea.x & 0xFFFFu) << 6) + c * 8); \
        uint2 q1 = *(const uint2*)((X8) + ((size_t)(ea.y & 0xFFFFu) << 6) + c * 8); \
        uint2 q2 = *(const uint2*)((X8) + ((size_t)(ea.z & 0xFFFFu) << 6) + c * 8); \
        uint2 q3 = *(const uint2*)((X8) + ((size_t)(ea.w & 0xFFFFu) << 6) + c * 8); \
        uint2 q4 = *(const uint2*)((X8) + ((size_t)(eb.x & 0xFFFFu) << 6) + c * 8); \
        uint2 q5 = *(const uint2*)((X8) + ((size_t)(eb.y & 0xFFFFu) << 6) + c * 8); \
        uint2 q6 = *(const uint2*)((X8) + ((size_t)(eb.z & 0xFFFFu) << 6) + c * 8); \
        uint2 q7 = *(const uint2*)((X8) + ((size_t)(eb.w & 0xFFFFu) << 6) + c * 8); \
        EDGE_FMA(b2f_hi(ea.x), q0); EDGE_FMA(b2f_hi(ea.y), q1);              \
        EDGE_FMA(b2f_hi(ea.z), q2); EDGE_FMA(b2f_hi(ea.w), q3);              \
        EDGE_FMA(b2f_hi(eb.x), q4); EDGE_FMA(b2f_hi(eb.y), q5);              \
        EDGE_FMA(b2f_hi(eb.z), q6); EDGE_FMA(b2f_hi(eb.w), q7);              \
        ea = na; eb = nb;                                                    \
      }                                                                      \
      if (j + 4 <= cnt) {                                                    \
        uint2 q0 = *(const uint2*)((X8) + ((size_t)(ea.x & 0xFFFFu) << 6) + c * 8); \
        uint2 q1 = *(const uint2*)((X8) + ((size_t)(ea.y & 0xFFFFu) << 6) + c * 8); \
        uint2 q2 = *(const uint2*)((X8) + ((size_t)(ea.z & 0xFFFFu) << 6) + c * 8); \
        uint2 q3 = *(const uint2*)((X8) + ((size_t)(ea.w & 0xFFFFu) << 6) + c * 8); \
        EDGE_FMA(b2f_hi(ea.x), q0); EDGE_FMA(b2f_hi(ea.y), q1);              \
        EDGE_FMA(b2f_hi(ea.z), q2); EDGE_FMA(b2f_hi(ea.w), q3);              \
        ea = eb;                                                             \
        j += 4;                                                              \
      }                                                                      \
      for (; j < cnt; ++j) {                                                 \
        uint e = ep[j];                                                      \
        uint2 q = *(const uint2*)((X8) + ((size_t)(e & 0xFFFFu) << 6) + c * 8); \
        EDGE_FMA(b2f_hi(e), q);                                              \
      }                                                                      \
    }

#define EDGE_FMA(v, q)                                                  \
    {                                                                   \
      f32x2 f0 = __builtin_amdgcn_cvt_pk_f32_fp8((q).x, false);         \
      f32x2 f1 = __builtin_amdgcn_cvt_pk_f32_fp8((q).x, true);          \
      f32x2 f2 = __builtin_amdgcn_cvt_pk_f32_fp8((q).y, false);         \
      f32x2 f3 = __builtin_amdgcn_cvt_pk_f32_fp8((q).y, true);          \
      a0 = fmaf(v, f0.x, a0); a1 = fmaf(v, f0.y, a1);                   \
      a2 = fmaf(v, f1.x, a2); a3 = fmaf(v, f1.y, a3);                   \
      a4 = fmaf(v, f2.x, a4); a5 = fmaf(v, f2.y, a5);                   \
      a6 = fmaf(v, f3.x, a6); a7 = fmaf(v, f3.y, a7);                   \
    }

// ---- k_lo: lower-half gather (X8a L2-resident) -> P1 (final Xp cols 0..63) ----
__global__ __launch_bounds__(256) void k_lo(
    const int* __restrict__ counts, const uint* __restrict__ ell,
    const ushort* __restrict__ Xdiag, const uchar* __restrict__ X8,
    const float* __restrict__ temps_l, ushort* __restrict__ P1) {
  const int t = threadIdx.x;
  const int nloc = t >> 3;
  const int c = t & 7;                    // owns cols c*8 .. c*8+7 (of 64)
  const int g = blockIdx.x * 32 + nloc;   // < NAL always (1564 blocks)
  const uint* ep = ell + (size_t)g * CAP;
  int cnt = counts[g];
  if (cnt > CAP) cnt = CAP;
  GATHER_HALF(X8)
  u32x4 pr = __builtin_nontemporal_load(
      (const u32x4*)(Xdiag + ((size_t)g << 7) + c * 8));
  float4 t0 = *(const float4*)(temps_l + c * 8);
  float4 t1 = *(const float4*)(temps_l + c * 8 + 4);
  u32x4 outv;
  outv.x = (uint)f2b(b2f_lo(pr.x) - t0.x * a0) | ((uint)f2b(b2f_hi(pr.x) - t0.y * a1) << 16);
  outv.y = (uint)f2b(b2f_lo(pr.y) - t0.z * a2) | ((uint)f2b(b2f_hi(pr.y) - t0.w * a3) << 16);
  outv.z = (uint)f2b(b2f_lo(pr.z) - t1.x * a4) | ((uint)f2b(b2f_hi(pr.z) - t1.y * a5) << 16);
  outv.w = (uint)f2b(b2f_lo(pr.w) - t1.z * a6) | ((uint)f2b(b2f_hi(pr.w) - t1.w * a7) << 16);
  __builtin_nontemporal_store(outv, (u32x4*)(P1 + (size_t)g * 64 + c * 8));
}

// ---- k_hi: upper-half gather (X8b L2-resident) + P1 assemble + MFMA GEMM ----
__global__ __launch_bounds__(256) void k_hi(
    const int* __restrict__ counts, const uint* __restrict__ ell,
    const ushort* __restrict__ Xdiag, const uchar* __restrict__ X8,
    const ushort* __restrict__ Wb, const float* __restrict__ bias,
    const float* __restrict__ temps_l, const ushort* __restrict__ P1,
    ushort* __restrict__ Yb, uchar* __restrict__ Y8a, uchar* __restrict__ Y8b,
    float* __restrict__ Yf, int store_f32) {
  __shared__ ushort Xs[32][136];
  const int t = threadIdx.x;

  // ---- phase A (upper half) ----
  {
    const int nloc = t >> 3;
    const int c = t & 7;
    const int g = blockIdx.x * 32 + nloc;
    const uint* ep = ell + (size_t)g * CAP;
    int cnt = counts[g];
    if (cnt > CAP) cnt = CAP;
    GATHER_HALF(X8)
    u32x4 pr = __builtin_nontemporal_load(
        (const u32x4*)(Xdiag + ((size_t)g << 7) + 64 + c * 8));
    float4 t0 = *(const float4*)(temps_l + 64 + c * 8);
    float4 t1 = *(const float4*)(temps_l + 64 + c * 8 + 4);
    u32x4 hv;
    hv.x = (uint)f2b(b2f_lo(pr.x) - t0.x * a0) | ((uint)f2b(b2f_hi(pr.x) - t0.y * a1) << 16);
    hv.y = (uint)f2b(b2f_lo(pr.y) - t0.z * a2) | ((uint)f2b(b2f_hi(pr.y) - t0.w * a3) << 16);
    hv.z = (uint)f2b(b2f_lo(pr.z) - t1.x * a4) | ((uint)f2b(b2f_hi(pr.z) - t1.y * a5) << 16);
    hv.w = (uint)f2b(b2f_lo(pr.w) - t1.z * a6) | ((uint)f2b(b2f_hi(pr.w) - t1.w * a7) << 16);
    *(u32x4*)&Xs[nloc][64 + c * 8] = hv;
    // lower half from P1 (nontemporal streaming read)
    u32x4 p1v = __builtin_nontemporal_load(
        (const u32x4*)(P1 + (size_t)g * 64 + c * 8));
    *(u32x4*)&Xs[nloc][c * 8] = p1v;
  }
  __syncthreads();

  // ---- phase B: 32x128 GEMM via MFMA; wave -> (row-tile, nt-half) ----
  const int wave = t >> 6;
  const int lane = t & 63;
  const int lr = lane & 15;
  const int kg = lane >> 4;
  const int rt = (wave >> 1) * 16;

  bf16x8 a0 = *(const bf16x8*)&Xs[rt + lr][0 + kg * 8];
  bf16x8 a1 = *(const bf16x8*)&Xs[rt + lr][32 + kg * 8];
  bf16x8 a2 = *(const bf16x8*)&Xs[rt + lr][64 + kg * 8];
  bf16x8 a3 = *(const bf16x8*)&Xs[rt + lr][96 + kg * 8];

  const int crow = kg * 4;
  #pragma unroll
  for (int q = 0; q < 4; ++q) {
    const int nt = (wave & 1) * 4 + q;
    const ushort* wp = Wb + ((size_t)(nt * 16 + lr) << 7) + kg * 8;
    bf16x8 b0 = *(const bf16x8*)(wp);
    bf16x8 b1 = *(const bf16x8*)(wp + 32);
    bf16x8 b2 = *(const bf16x8*)(wp + 64);
    bf16x8 b3 = *(const bf16x8*)(wp + 96);
    f32x4 acc = {0.f, 0.f, 0.f, 0.f};
    acc = __builtin_amdgcn_mfma_f32_16x16x32_bf16(a0, b0, acc, 0, 0, 0);
    acc = __builtin_amdgcn_mfma_f32_16x16x32_bf16(a1, b1, acc, 0, 0, 0);
    acc = __builtin_amdgcn_mfma_f32_16x16x32_bf16(a2, b2, acc, 0, 0, 0);
    acc = __builtin_amdgcn_mfma_f32_16x16x32_bf16(a3, b3, acc, 0, 0, 0);
    const int col = nt * 16 + lr;
    const float bv = bias[col];
    if (store_f32) {
      #pragma unroll
      for (int r = 0; r < 4; ++r) {
        int grow = blockIdx.x * 32 + rt + crow + r;
        if (grow < N_NODES)
          Yf[((size_t)grow << 7) + col] = fmaxf(acc[r] + bv, 0.f);
      }
    } else {
      #pragma unroll
      for (int r = 0; r < 4; ++r) {
        int grow = blockIdx.x * 32 + rt + crow + r;   // < NAL; buffers padded
        float o = fmaxf(acc[r] + bv, 0.f);
        Yb[((size_t)grow << 7) + col] = f2b(o);
        int pk = __builtin_amdgcn_cvt_pk_fp8_f32(o, o, 0, false);
        uchar byte = (uchar)(pk & 0xff);
        if (col < 64) Y8a[(size_t)grow * 64 + col] = byte;
        else          Y8b[(size_t)grow * 64 + col - 64] = byte;
      }
    }
  }
}

extern "C" void kernel_launch(void* const* d_in, const int* in_sizes, int n_in,
                              void* d_out, int out_size, void* d_ws, size_t ws_size,
                              hipStream_t stream) {
  const int*   row   = (const int*)d_in[0];
  const int*   col   = (const int*)d_in[1];
  const float* vals  = (const float*)d_in[2];
  const float* X     = (const float*)d_in[3];
  const float* temps = (const float*)d_in[4];
  const float* W     = (const float*)d_in[5];
  const float* b     = (const float*)d_in[6];
  float* Y = (float*)d_out;

  // workspace layout — all section sizes multiples of 256 B.
  int*    counts  = (int*)d_ws;                          // 200,192 B
  int*    bcnt    = counts + NAL;                        // 256 KB
  uint2*  staging = (uint2*)(bcnt + NB1 * NBINS);        // 16 MB
  uint*   ell     = (uint*)(staging + (size_t)NB1 * NBINS * FRAG_CAP); // 9.6 MB
  ushort* Xb      = (ushort*)(ell + (size_t)NAL * CAP);  // 12.8 MB (diag, bf16)
  ushort* Yb      = Xb + (size_t)NAL * D;                // 12.8 MB
  ushort* Wb      = Yb + (size_t)NAL * D;                // 128 KB
  ushort* P1      = Wb + LAYERS * D * D;                 // 6.4 MB (half-row bf16)
  uchar*  X8a     = (uchar*)(P1 + (size_t)NAL * 64);     // 3.2 MB
  uchar*  X8b     = X8a + (size_t)NAL * 64;              // 3.2 MB
  uchar*  Y8a     = X8b + (size_t)NAL * 64;              // 3.2 MB
  uchar*  Y8b     = Y8a + (size_t)NAL * 64;              // 3.2 MB
  // total ~71 MB

  const int hblocks = NAL / 32;                          // 1564

  k_bin_prep<<<NB1 + PBLOCKS, 256, 0, stream>>>(row, col, vals, staging, bcnt,
                                                X, W, Xb, Wb,
                                                (uint*)X8a, (uint*)X8b);
  k_scatter<<<NBINS, 256, 0, stream>>>(staging, bcnt, counts, ell);

  // layer 1
  k_lo<<<hblocks, 256, 0, stream>>>(counts, ell, Xb, X8a, temps, P1);
  k_hi<<<hblocks, 256, 0, stream>>>(counts, ell, Xb, X8b, Wb, b, temps, P1,
                                    Yb, Y8a, Y8b, nullptr, 0);
  // layer 2
  k_lo<<<hblocks, 256, 0, stream>>>(counts, ell, Yb, Y8a, temps + D, P1);
  k_hi<<<hblocks, 256, 0, stream>>>(counts, ell, Yb, Y8b, Wb + D * D, b + D,
                                    temps + D, P1, nullptr, nullptr, nullptr,
                                    Y, 1);
}

// Round 21
// 87.552 us; speedup vs baseline: 1.1903x; 1.1903x over previous
//
#include <hip/hip_runtime.h>

#define N_NODES 50000
#define N_EDGES 600000
#define D 128
#define LAYERS 2
#define NAL 50048     // N_NODES rounded up to 64
#define CAP 48        // ELL slots per row
#define NB1 256       // phase-1 binning blocks
#define EPB 2344      // edges per binning block (256*2344 >= 600000)
#define NBINS 256
#define BIN_ROWS 196  // 256*196 = 50176 >= N_NODES
#define FRAG_CAP 32   // per-(block,bin) fragment cap; Poisson(9.2) -> P(>32)~1e-10
#define PBLOCKS 6250  // prep: 1.6M float4 elements / 256

typedef short bf16x8 __attribute__((ext_vector_type(8)));
typedef float f32x4 __attribute__((ext_vector_type(4)));
typedef float f32x2 __attribute__((ext_vector_type(2)));

__device__ __forceinline__ ushort f2b(float f) {
  uint u = __float_as_uint(f);
  return (ushort)((u + 0x7fffu + ((u >> 16) & 1u)) >> 16);
}
__device__ __forceinline__ float b2f_lo(uint p) { return __uint_as_float(p << 16); }
__device__ __forceinline__ float b2f_hi(uint p) { return __uint_as_float(p & 0xffff0000u); }

// ---- dispatch 1: edge binning (blocks 0..255, LDS cursors only) + prep ----
__global__ __launch_bounds__(256) void k_bin_prep(
    const int* __restrict__ row, const int* __restrict__ col,
    const float* __restrict__ vals,
    uint2* __restrict__ staging, int* __restrict__ bcnt,
    const float* __restrict__ X, const float* __restrict__ W,
    ushort* __restrict__ Xb, ushort* __restrict__ Wb, uint* __restrict__ Xf8) {
  const int blk = blockIdx.x;
  const int t = threadIdx.x;
  if (blk < NB1) {
    __shared__ int lcur[NBINS];
    lcur[t] = 0;                       // 256 threads == NBINS
    __syncthreads();
    const int e0 = blk * EPB;
    for (int i = t; i < EPB; i += 256) {
      int e = e0 + i;
      if (e < N_EDGES) {
        int r = row[e];
        int bin = r / BIN_ROWS;        // 0..255 (compiler magic-mul)
        int slot = atomicAdd(&lcur[bin], 1);   // LDS atomic
        if (slot < FRAG_CAP) {
          uint cv = ((uint)f2b(vals[e]) << 16) | (uint)col[e];
          staging[((size_t)blk * NBINS + bin) * FRAG_CAP + slot] =
              make_uint2(cv, (uint)r);
        }
      }
    }
    __syncthreads();
    bcnt[blk * NBINS + t] = min(lcur[t], FRAG_CAP);
  } else {
    // ---- prep: convert X -> bf16 + fp8, W -> bf16 ----
    int i = (blk - NB1) * 256 + t;
    if (i < N_NODES * D / 4) {
      float4 v = ((const float4*)X)[i];
      ushort4 o;
      o.x = f2b(v.x); o.y = f2b(v.y); o.z = f2b(v.z); o.w = f2b(v.w);
      ((ushort4*)Xb)[i] = o;
      int pk = __builtin_amdgcn_cvt_pk_fp8_f32(v.x, v.y, 0, false);
      pk = __builtin_amdgcn_cvt_pk_fp8_f32(v.z, v.w, pk, true);
      Xf8[i] = (uint)pk;
    }
    if (i < LAYERS * D * D / 4) {
      float4 v = ((const float4*)W)[i];
      ushort4 o;
      o.x = f2b(v.x); o.y = f2b(v.y); o.z = f2b(v.z); o.w = f2b(v.w);
      ((ushort4*)Wb)[i] = o;
    }
  }
}

// ---- dispatch 2: per-bin ELL scatter (LDS cursors, L2-hot windows) ----
__global__ __launch_bounds__(256) void k_scatter(
    const uint2* __restrict__ staging, const int* __restrict__ bcnt,
    int* __restrict__ counts, uint* __restrict__ ell) {
  const int b = blockIdx.x;            // bin
  const int t = threadIdx.x;
  __shared__ int lcur[BIN_ROWS];
  for (int i = t; i < BIN_ROWS; i += 256) lcur[i] = 0;
  __syncthreads();
  const int rbase = b * BIN_ROWS;
  const int n = bcnt[t * NBINS + b];
  const uint2* frag = staging + ((size_t)t * NBINS + b) * FRAG_CAP;
  for (int k = 0; k < n; ++k) {
    uint2 E = frag[k];
    int rl = (int)E.y - rbase;
    int slot = atomicAdd(&lcur[rl], 1);          // LDS atomic
    if (slot < CAP) ell[(size_t)E.y * CAP + slot] = E.x;
  }
  __syncthreads();
  for (int i = t; i < BIN_ROWS; i += 256) {
    int r = rbase + i;
    if (r < NAL) counts[r] = lcur[i];
  }
}

// ---------------- fused layer (fp8 gather + bf16 diag/GEMM) ----------------
// 256 threads, 16 nodes/block, 16 threads/node. Phase A: 8-edge
// software-pipelined batches (8 independent line-gathers in flight; FMA
// consumption stays in strict slot order -> bit-identical accumulation).
// Phase B: 4 waves do the 16x128 MFMA GEMM.
__global__ __launch_bounds__(256) void k_layer(
    const int* __restrict__ counts, const uint* __restrict__ ell,
    const ushort* __restrict__ Xin, const uchar* __restrict__ Xg8,
    const ushort* __restrict__ Wb, const float* __restrict__ bias,
    const float* __restrict__ temps_l,
    ushort* __restrict__ Yb, uchar* __restrict__ Yf8,
    float* __restrict__ Yf, int store_f32) {
  __shared__ ushort Xs[16][136];
  const int t = threadIdx.x;

  // ---- phase A ----
  {
    const int nloc = t >> 4;
    const int c = t & 15;                   // owns cols c*8 .. c*8+7
    const int g = blockIdx.x * 16 + nloc;   // < NAL always (3128 blocks)
    const uint* ep = ell + (size_t)g * CAP;
    int cnt = counts[g];
    if (cnt > CAP) cnt = CAP;
    float a0 = 0.f, a1 = 0.f, a2 = 0.f, a3 = 0.f;
    float a4 = 0.f, a5 = 0.f, a6 = 0.f, a7 = 0.f;
#define EDGE_FMA(v, q)                                                  \
    {                                                                   \
      f32x2 f0 = __builtin_amdgcn_cvt_pk_f32_fp8((q).x, false);         \
      f32x2 f1 = __builtin_amdgcn_cvt_pk_f32_fp8((q).x, true);          \
      f32x2 f2 = __builtin_amdgcn_cvt_pk_f32_fp8((q).y, false);         \
      f32x2 f3 = __builtin_amdgcn_cvt_pk_f32_fp8((q).y, true);          \
      a0 = fmaf(v, f0.x, a0); a1 = fmaf(v, f0.y, a1);                   \
      a2 = fmaf(v, f1.x, a2); a3 = fmaf(v, f1.y, a3);                   \
      a4 = fmaf(v, f2.x, a4); a5 = fmaf(v, f2.y, a5);                   \
      a6 = fmaf(v, f3.x, a6); a7 = fmaf(v, f3.y, a7);                   \
    }
    // 8-edge pipelined main loop; descriptor over-reads stay in mapped ws.
    uint4 ea = *(const uint4*)(ep);
    uint4 eb = *(const uint4*)(ep + 4);
    int j = 0;
    for (; j + 8 <= cnt; j += 8) {
      uint4 na = *(const uint4*)(ep + j + 8);
      uint4 nb = *(const uint4*)(ep + j + 12);
      uint2 q0 = *(const uint2*)(Xg8 + ((size_t)(ea.x & 0xFFFFu) << 7) + c * 8);
      uint2 q1 = *(const uint2*)(Xg8 + ((size_t)(ea.y & 0xFFFFu) << 7) + c * 8);
      uint2 q2 = *(const uint2*)(Xg8 + ((size_t)(ea.z & 0xFFFFu) << 7) + c * 8);
      uint2 q3 = *(const uint2*)(Xg8 + ((size_t)(ea.w & 0xFFFFu) << 7) + c * 8);
      uint2 q4 = *(const uint2*)(Xg8 + ((size_t)(eb.x & 0xFFFFu) << 7) + c * 8);
      uint2 q5 = *(const uint2*)(Xg8 + ((size_t)(eb.y & 0xFFFFu) << 7) + c * 8);
      uint2 q6 = *(const uint2*)(Xg8 + ((size_t)(eb.z & 0xFFFFu) << 7) + c * 8);
      uint2 q7 = *(const uint2*)(Xg8 + ((size_t)(eb.w & 0xFFFFu) << 7) + c * 8);
      EDGE_FMA(b2f_hi(ea.x), q0); EDGE_FMA(b2f_hi(ea.y), q1);
      EDGE_FMA(b2f_hi(ea.z), q2); EDGE_FMA(b2f_hi(ea.w), q3);
      EDGE_FMA(b2f_hi(eb.x), q4); EDGE_FMA(b2f_hi(eb.y), q5);
      EDGE_FMA(b2f_hi(eb.z), q6); EDGE_FMA(b2f_hi(eb.w), q7);
      ea = na; eb = nb;
    }
    if (j + 4 <= cnt) {
      uint2 q0 = *(const uint2*)(Xg8 + ((size_t)(ea.x & 0xFFFFu) << 7) + c * 8);
      uint2 q1 = *(const uint2*)(Xg8 + ((size_t)(ea.y & 0xFFFFu) << 7) + c * 8);
      uint2 q2 = *(const uint2*)(Xg8 + ((size_t)(ea.z & 0xFFFFu) << 7) + c * 8);
      uint2 q3 = *(const uint2*)(Xg8 + ((size_t)(ea.w & 0xFFFFu) << 7) + c * 8);
      EDGE_FMA(b2f_hi(ea.x), q0); EDGE_FMA(b2f_hi(ea.y), q1);
      EDGE_FMA(b2f_hi(ea.z), q2); EDGE_FMA(b2f_hi(ea.w), q3);
      ea = eb;
      j += 4;
    }
    for (; j < cnt; ++j) {
      uint e = ep[j];
      uint2 q = *(const uint2*)(Xg8 + ((size_t)(e & 0xFFFFu) << 7) + c * 8);
      EDGE_FMA(b2f_hi(e), q);
    }
#undef EDGE_FMA
    uint4 pr = *(const uint4*)(Xin + ((size_t)g << 7) + c * 8);
    float4 t0 = *(const float4*)(temps_l + c * 8);
    float4 t1 = *(const float4*)(temps_l + c * 8 + 4);
    uint r0 = (uint)f2b(b2f_lo(pr.x) - t0.x * a0) | ((uint)f2b(b2f_hi(pr.x) - t0.y * a1) << 16);
    uint r1 = (uint)f2b(b2f_lo(pr.y) - t0.z * a2) | ((uint)f2b(b2f_hi(pr.y) - t0.w * a3) << 16);
    uint r2 = (uint)f2b(b2f_lo(pr.z) - t1.x * a4) | ((uint)f2b(b2f_hi(pr.z) - t1.y * a5) << 16);
    uint r3 = (uint)f2b(b2f_lo(pr.w) - t1.z * a6) | ((uint)f2b(b2f_hi(pr.w) - t1.w * a7) << 16);
    *(uint4*)&Xs[nloc][c * 8] = make_uint4(r0, r1, r2, r3);
  }
  __syncthreads();

  // ---- phase B: 16x128 GEMM tile via MFMA ----
  const int wave = t >> 6;
  const int lane = t & 63;
  const int lr = lane & 15;
  const int kg = lane >> 4;

  bf16x8 a0 = *(const bf16x8*)&Xs[lr][0 + kg * 8];
  bf16x8 a1 = *(const bf16x8*)&Xs[lr][32 + kg * 8];
  bf16x8 a2 = *(const bf16x8*)&Xs[lr][64 + kg * 8];
  bf16x8 a3 = *(const bf16x8*)&Xs[lr][96 + kg * 8];

  const int crow = kg * 4;
  #pragma unroll
  for (int q = 0; q < 2; ++q) {
    const int nt = wave * 2 + q;
    const ushort* wp = Wb + ((size_t)(nt * 16 + lr) << 7) + kg * 8;
    bf16x8 b0 = *(const bf16x8*)(wp);
    bf16x8 b1 = *(const bf16x8*)(wp + 32);
    bf16x8 b2 = *(const bf16x8*)(wp + 64);
    bf16x8 b3 = *(const bf16x8*)(wp + 96);
    f32x4 acc = {0.f, 0.f, 0.f, 0.f};
    acc = __builtin_amdgcn_mfma_f32_16x16x32_bf16(a0, b0, acc, 0, 0, 0);
    acc = __builtin_amdgcn_mfma_f32_16x16x32_bf16(a1, b1, acc, 0, 0, 0);
    acc = __builtin_amdgcn_mfma_f32_16x16x32_bf16(a2, b2, acc, 0, 0, 0);
    acc = __builtin_amdgcn_mfma_f32_16x16x32_bf16(a3, b3, acc, 0, 0, 0);
    const int col = nt * 16 + lr;
    const float bv = bias[col];
    if (store_f32) {
      #pragma unroll
      for (int r = 0; r < 4; ++r) {
        int grow = blockIdx.x * 16 + crow + r;
        if (grow < N_NODES)
          Yf[((size_t)grow << 7) + col] = fmaxf(acc[r] + bv, 0.f);
      }
    } else {
      #pragma unroll
      for (int r = 0; r < 4; ++r) {
        int grow = blockIdx.x * 16 + crow + r;   // < NAL always; Yb/Yf8 padded
        float o = fmaxf(acc[r] + bv, 0.f);
        Yb[((size_t)grow << 7) + col] = f2b(o);
        int pk = __builtin_amdgcn_cvt_pk_fp8_f32(o, o, 0, false);
        Yf8[((size_t)grow << 7) + col] = (uchar)(pk & 0xff);
      }
    }
  }
}

extern "C" void kernel_launch(void* const* d_in, const int* in_sizes, int n_in,
                              void* d_out, int out_size, void* d_ws, size_t ws_size,
                              hipStream_t stream) {
  const int*   row   = (const int*)d_in[0];
  const int*   col   = (const int*)d_in[1];
  const float* vals  = (const float*)d_in[2];
  const float* X     = (const float*)d_in[3];
  const float* temps = (const float*)d_in[4];
  const float* W     = (const float*)d_in[5];
  const float* b     = (const float*)d_in[6];
  float* Y = (float*)d_out;

  // workspace layout — all section sizes multiples of 256 B (row alignment).
  int*    counts  = (int*)d_ws;                          // 200,192 B
  int*    bcnt    = counts + NAL;                        // 256 KB
  uint2*  staging = (uint2*)(bcnt + NB1 * NBINS);        // 16 MB
  uint*   ell     = (uint*)(staging + (size_t)NB1 * NBINS * FRAG_CAP); // 9.6 MB
  ushort* Xb      = (ushort*)(ell + (size_t)NAL * CAP);  // 12.8 MB
  ushort* Yb      = Xb + (size_t)NAL * D;                // 12.8 MB
  ushort* Wb      = Yb + (size_t)NAL * D;                // 128 KB
  uchar*  Xf8     = (uchar*)(Wb + LAYERS * D * D);       // 6.4 MB
  uchar*  Yf8     = Xf8 + (size_t)NAL * D;               // 6.4 MB
  // total ~65 MB

  const int lblocks = NAL / 16;                          // 3128

  k_bin_prep<<<NB1 + PBLOCKS, 256, 0, stream>>>(row, col, vals, staging, bcnt,
                                                X, W, Xb, Wb, (uint*)Xf8);
  k_scatter<<<NBINS, 256, 0, stream>>>(staging, bcnt, counts, ell);

  // layer 1: gather Xf8 / diag Xb -> Yb + Yf8
  k_layer<<<lblocks, 256, 0, stream>>>(counts, ell, Xb, Xf8, Wb, b, temps,
                                       Yb, Yf8, nullptr, 0);
  // layer 2: gather Yf8 / diag Yb -> Y (fp32)
  k_layer<<<lblocks, 256, 0, stream>>>(counts, ell, Yb, Yf8, Wb + D * D, b + D,
                                       temps + D, nullptr, nullptr, Y, 1);
}